// Round 1
// baseline (172.279 us; speedup 1.0000x reference)
//
#include <hip/hip_runtime.h>

#define NPOS 589824   // 64*96*96
#define LN_EPS 1e-5f

typedef _Float16 half8 __attribute__((ext_vector_type(8)));
typedef float f32x4 __attribute__((ext_vector_type(4)));

#define K1_BLOCKS 768
#define CPB 3   // chunks of 256 positions per block  (768*3*256 == NPOS)

// ws layout (floats): [0,1024) G 32x32 ; [1024,2432) M 64x22 ; [2432,2496) beta
// [4096, 4096 + K1_BLOCKS*1024) partials
__global__ __launch_bounds__(256) void csa_k1(
    const float* __restrict__ x, const float* __restrict__ lng,
    const float* __restrict__ lnb, float* __restrict__ partials,
    float* __restrict__ gfin, int partial_mode)
{
    __shared__ __align__(16) _Float16 Aar[32][264];  // y ch 0..21, row22=ones, 23..31=0
    __shared__ __align__(16) _Float16 Bar[32][264];  // y ch 21..42, row22=ones
    const int tid = threadIdx.x;
    const int lane = tid & 63;
    const int wv = tid >> 6;

    #pragma unroll
    for (int r = 22; r < 32; ++r) {
        const _Float16 v = (r == 22) ? (_Float16)1.0f : (_Float16)0.0f;
        for (int ci = tid; ci < 264; ci += 256) { Aar[r][ci] = v; Bar[r][ci] = v; }
    }
    f32x4 acc00 = {0.f,0.f,0.f,0.f}, acc01 = acc00, acc10 = acc00, acc11 = acc00;
    const int row = lane & 15;
    const int kbase = wv * 64 + ((lane >> 4) << 3);  // this wave's K offset
    const int pos0 = blockIdx.x * (CPB * 256);

    for (int ck = 0; ck < CPB; ++ck) {
        const int n = pos0 + ck * 256 + tid;
        float s = 0.f, sq = 0.f;
        float xv[43];
        #pragma unroll
        for (int c = 0; c < 43; ++c) {
            float v = x[c * NPOS + n];
            xv[c] = v; s += v; sq = fmaf(v, v, sq);
        }
        #pragma unroll
        for (int c = 43; c < 64; ++c) {
            float v = x[c * NPOS + n];
            s += v; sq = fmaf(v, v, sq);
        }
        const float mu  = s * (1.f/64.f);
        const float var = fmaf(-mu, mu, sq * (1.f/64.f));
        const float rin = rsqrtf(fmaxf(var, 0.f) + LN_EPS);
        #pragma unroll
        for (int c = 0; c < 43; ++c) {
            float yv = fmaf((xv[c] - mu) * rin, lng[c], lnb[c]);
            _Float16 h = (_Float16)yv;
            if (c < 22)  Aar[c][tid] = h;        // channels 0..21
            if (c >= 21) Bar[c - 21][tid] = h;   // channels 21..42
        }
        __syncthreads();
        #pragma unroll
        for (int s2 = 0; s2 < 2; ++s2) {
            const int kk = kbase + s2 * 32;
            half8 a0 = *(const half8*)&Aar[row][kk];
            half8 a1 = *(const half8*)&Aar[row + 16][kk];
            half8 b0 = *(const half8*)&Bar[row][kk];
            half8 b1 = *(const half8*)&Bar[row + 16][kk];
            acc00 = __builtin_amdgcn_mfma_f32_16x16x32_f16(a0, b0, acc00, 0, 0, 0);
            acc01 = __builtin_amdgcn_mfma_f32_16x16x32_f16(a0, b1, acc01, 0, 0, 0);
            acc10 = __builtin_amdgcn_mfma_f32_16x16x32_f16(a1, b0, acc10, 0, 0, 0);
            acc11 = __builtin_amdgcn_mfma_f32_16x16x32_f16(a1, b1, acc11, 0, 0, 0);
        }
        __syncthreads();
    }
    // block-level reduce of the 4 waves' fragments
    float* G32 = (float*)&Aar[0][0];
    for (int e = tid; e < 1024; e += 256) G32[e] = 0.f;
    __syncthreads();
    const int r0 = (lane >> 4) * 4, c0 = lane & 15;
    #pragma unroll
    for (int r = 0; r < 4; ++r) {
        atomicAdd(&G32[(r0 + r) * 32 + c0],            acc00[r]);
        atomicAdd(&G32[(r0 + r) * 32 + 16 + c0],       acc01[r]);
        atomicAdd(&G32[(16 + r0 + r) * 32 + c0],       acc10[r]);
        atomicAdd(&G32[(16 + r0 + r) * 32 + 16 + c0],  acc11[r]);
    }
    __syncthreads();
    if (partial_mode) {
        for (int e = tid; e < 1024; e += 256) partials[blockIdx.x * 1024 + e] = G32[e];
    } else {
        for (int e = tid; e < 1024; e += 256) atomicAdd(&gfin[e], G32[e]);
    }
}

__global__ __launch_bounds__(256) void csa_k2(const float* __restrict__ partials,
                                              float* __restrict__ gfin)
{
    const int e = blockIdx.x * 256 + threadIdx.x;  // 0..1023
    float s = 0.f;
    for (int b = 0; b < K1_BLOCKS; ++b) s += partials[b * 1024 + e];
    gfin[e] = s;
}

__global__ void csa_k3(const float* __restrict__ G, const float* __restrict__ cw,
                       const float* __restrict__ cb, float* __restrict__ M,
                       float* __restrict__ betaO)
{
    const int c = threadIdx.x;       // 64 threads, one output row each
    __shared__ float lg[64][65];
    const float wq = cw[c], bq = cb[c];
    const int a = c / 3;             // 0..21
    const float Sa = G[a * 32 + 22]; // sum of y_a (from ones column)
    float mx = -1e30f;
    #pragma unroll
    for (int k = 0; k < 64; ++k) {
        const float wk = cw[64 + k], bk = cb[64 + k];
        const int b = (64 + k) / 3 - 21;      // 0..21
        const float Gab = G[a * 32 + b];
        const float Sb  = G[22 * 32 + b];
        float lo = 0.125f * (wq * wk * Gab + wq * bk * Sa + bq * wk * Sb
                             + bq * bk * (float)NPOS);
        lg[c][k] = lo;
        mx = fmaxf(mx, lo);
    }
    float sum = 0.f;
    #pragma unroll
    for (int k = 0; k < 64; ++k) {
        float e = expf(lg[c][k] - mx);
        lg[c][k] = e; sum += e;
    }
    const float inv = 1.f / sum;
    float Ml[22];
    #pragma unroll
    for (int m = 0; m < 22; ++m) Ml[m] = 0.f;
    float bacc = 0.f;
    #pragma unroll
    for (int k = 0; k < 64; ++k) {
        const float attn = lg[c][k] * inv;
        const int mm = (128 + k) / 3 - 42;    // 0..21 (v channel 42..63)
        Ml[mm] = fmaf(attn, cw[128 + k], Ml[mm]);
        bacc   = fmaf(attn, cb[128 + k], bacc);
    }
    #pragma unroll
    for (int m = 0; m < 22; ++m) M[c * 22 + m] = Ml[m];
    betaO[c] = bacc;
}

__global__ __launch_bounds__(256) void csa_k4(
    const float* __restrict__ x, const float* __restrict__ lng,
    const float* __restrict__ lnb, const float* __restrict__ M,
    const float* __restrict__ betaO, float* __restrict__ out)
{
    const int n = blockIdx.x * 256 + threadIdx.x;
    float xv[64];
    float s = 0.f, sq = 0.f;
    #pragma unroll
    for (int c = 0; c < 64; ++c) {
        float v = x[c * NPOS + n];
        xv[c] = v; s += v; sq = fmaf(v, v, sq);
    }
    const float mu  = s * (1.f/64.f);
    const float var = fmaf(-mu, mu, sq * (1.f/64.f));
    const float rin = rsqrtf(fmaxf(var, 0.f) + LN_EPS);
    float y[22];
    #pragma unroll
    for (int m = 0; m < 22; ++m)
        y[m] = fmaf((xv[42 + m] - mu) * rin, lng[42 + m], lnb[42 + m]);
    #pragma unroll
    for (int c = 0; c < 64; ++c) {
        float acc = betaO[c];
        #pragma unroll
        for (int m = 0; m < 22; ++m)
            acc = fmaf(M[c * 22 + m], y[m], acc);   // uniform -> s_load + SGPR FMA
        out[c * NPOS + n] = xv[c] + acc;
    }
}

extern "C" void kernel_launch(void* const* d_in, const int* in_sizes, int n_in,
                              void* d_out, int out_size, void* d_ws, size_t ws_size,
                              hipStream_t stream) {
    const float* x   = (const float*)d_in[0];
    const float* lng = (const float*)d_in[1];
    const float* lnb = (const float*)d_in[2];
    const float* cw  = (const float*)d_in[3];
    const float* cb  = (const float*)d_in[4];
    float* out = (float*)d_out;

    float* wsf = (float*)d_ws;
    float* Gf  = wsf;                     // 1024 floats
    float* Mf  = wsf + 1024;              // 64*22
    float* Bf  = wsf + 1024 + 64 * 22;    // 64
    float* Pf  = wsf + 4096;              // partials

    const size_t need = 16384 + (size_t)K1_BLOCKS * 1024 * 4;
    const int partial = (ws_size >= need) ? 1 : 0;
    if (!partial) hipMemsetAsync(Gf, 0, 1024 * sizeof(float), stream);

    hipLaunchKernelGGL(csa_k1, dim3(K1_BLOCKS), dim3(256), 0, stream,
                       x, lng, lnb, Pf, Gf, partial);
    if (partial)
        hipLaunchKernelGGL(csa_k2, dim3(4), dim3(256), 0, stream, Pf, Gf);
    hipLaunchKernelGGL(csa_k3, dim3(1), dim3(64), 0, stream, Gf, cw, cb, Mf, Bf);
    hipLaunchKernelGGL(csa_k4, dim3(NPOS / 256), dim3(256), 0, stream,
                       x, lng, lnb, Mf, Bf, out);
}

// Round 2
// 170.741 us; speedup vs baseline: 1.0090x; 1.0090x over previous
//
#include <hip/hip_runtime.h>

#define NPOS 589824   // 64*96*96
#define LN_EPS 1e-5f

typedef _Float16 half8 __attribute__((ext_vector_type(8)));
typedef float f32x4 __attribute__((ext_vector_type(4)));
typedef float f32x2 __attribute__((ext_vector_type(2)));

#define K1_BLOCKS 768
#define CPB 3   // chunks of 256 positions per block  (768*3*256 == NPOS)

// ---------------------------------------------------------------------------
// NEW PATH: stats kernel -> gram kernel -> k3 -> k4 (stats-fed)
// ---------------------------------------------------------------------------

// One thread = 4 consecutive positions. Pure streaming, no dependencies.
__global__ __launch_bounds__(256) void csa_stats(
    const float* __restrict__ x, float* __restrict__ stats /*2 floats per pos*/)
{
    const int g = blockIdx.x * 256 + threadIdx.x;        // 0 .. NPOS/4-1
    const f32x4* __restrict__ x4 = (const f32x4*)x;
    f32x4 s = {0.f,0.f,0.f,0.f}, sq = s;
    #pragma unroll
    for (int c = 0; c < 64; ++c) {
        f32x4 v = x4[c * (NPOS/4) + g];
        s += v;
        sq += v * v;
    }
    f32x4 mu = s * (1.f/64.f);
    f32x4 var = sq * (1.f/64.f) - mu * mu;
    f32x4 rin;
    #pragma unroll
    for (int j = 0; j < 4; ++j) rin[j] = rsqrtf(fmaxf(var[j], 0.f) + LN_EPS);
    f32x4* st4 = (f32x4*)stats;
    f32x4 o0 = {mu[0], rin[0], mu[1], rin[1]};
    f32x4 o1 = {mu[2], rin[2], mu[3], rin[3]};
    st4[2*g]     = o0;
    st4[2*g + 1] = o1;
}

// Gram over y channels 0..42 (+ ones row) using precomputed stats.
__global__ __launch_bounds__(256) void csa_gram(
    const float* __restrict__ x, const float* __restrict__ lng,
    const float* __restrict__ lnb, const float* __restrict__ stats,
    float* __restrict__ partials, float* __restrict__ gfin, int partial_mode)
{
    __shared__ __align__(16) _Float16 Aar[32][264];  // y ch 0..21, row22=ones, 23..31=0
    __shared__ __align__(16) _Float16 Bar[32][264];  // y ch 21..42, row22=ones
    const int tid = threadIdx.x;
    const int lane = tid & 63;
    const int wv = tid >> 6;

    #pragma unroll
    for (int r = 22; r < 32; ++r) {
        const _Float16 v = (r == 22) ? (_Float16)1.0f : (_Float16)0.0f;
        for (int ci = tid; ci < 264; ci += 256) { Aar[r][ci] = v; Bar[r][ci] = v; }
    }
    f32x4 acc00 = {0.f,0.f,0.f,0.f}, acc01 = acc00, acc10 = acc00, acc11 = acc00;
    const int row = lane & 15;
    const int kbase = wv * 64 + ((lane >> 4) << 3);
    const int pos0 = blockIdx.x * (CPB * 256);
    const f32x2* __restrict__ st2 = (const f32x2*)stats;

    for (int ck = 0; ck < CPB; ++ck) {
        const int n = pos0 + ck * 256 + tid;
        const f32x2 st = st2[n];
        const float mu = st[0], rin = st[1];
        #pragma unroll
        for (int c = 0; c < 43; ++c) {
            float v = x[c * NPOS + n];
            float yv = fmaf((v - mu) * rin, lng[c], lnb[c]);
            _Float16 h = (_Float16)yv;
            if (c < 22)  Aar[c][tid] = h;
            if (c >= 21) Bar[c - 21][tid] = h;
        }
        __syncthreads();
        #pragma unroll
        for (int s2 = 0; s2 < 2; ++s2) {
            const int kk = kbase + s2 * 32;
            half8 a0 = *(const half8*)&Aar[row][kk];
            half8 a1 = *(const half8*)&Aar[row + 16][kk];
            half8 b0 = *(const half8*)&Bar[row][kk];
            half8 b1 = *(const half8*)&Bar[row + 16][kk];
            acc00 = __builtin_amdgcn_mfma_f32_16x16x32_f16(a0, b0, acc00, 0, 0, 0);
            acc01 = __builtin_amdgcn_mfma_f32_16x16x32_f16(a0, b1, acc01, 0, 0, 0);
            acc10 = __builtin_amdgcn_mfma_f32_16x16x32_f16(a1, b0, acc10, 0, 0, 0);
            acc11 = __builtin_amdgcn_mfma_f32_16x16x32_f16(a1, b1, acc11, 0, 0, 0);
        }
        __syncthreads();
    }
    float* G32 = (float*)&Aar[0][0];
    for (int e = tid; e < 1024; e += 256) G32[e] = 0.f;
    __syncthreads();
    const int r0 = (lane >> 4) * 4, c0 = lane & 15;
    #pragma unroll
    for (int r = 0; r < 4; ++r) {
        atomicAdd(&G32[(r0 + r) * 32 + c0],            acc00[r]);
        atomicAdd(&G32[(r0 + r) * 32 + 16 + c0],       acc01[r]);
        atomicAdd(&G32[(16 + r0 + r) * 32 + c0],       acc10[r]);
        atomicAdd(&G32[(16 + r0 + r) * 32 + 16 + c0],  acc11[r]);
    }
    __syncthreads();
    if (partial_mode) {
        for (int e = tid; e < 1024; e += 256) partials[blockIdx.x * 1024 + e] = G32[e];
    } else {
        for (int e = tid; e < 1024; e += 256) atomicAdd(&gfin[e], G32[e]);
    }
}

__global__ __launch_bounds__(256) void csa_k2(const float* __restrict__ partials,
                                              float* __restrict__ gfin)
{
    const int e = blockIdx.x * 256 + threadIdx.x;  // 0..1023
    float s = 0.f;
    for (int b = 0; b < K1_BLOCKS; ++b) s += partials[b * 1024 + e];
    gfin[e] = s;
}

__global__ void csa_k3(const float* __restrict__ G, const float* __restrict__ cw,
                       const float* __restrict__ cb, float* __restrict__ M,
                       float* __restrict__ betaO)
{
    const int c = threadIdx.x;       // 64 threads, one output row each
    __shared__ float lg[64][65];
    const float wq = cw[c], bq = cb[c];
    const int a = c / 3;
    const float Sa = G[a * 32 + 22];
    float mx = -1e30f;
    #pragma unroll
    for (int k = 0; k < 64; ++k) {
        const float wk = cw[64 + k], bk = cb[64 + k];
        const int b = (64 + k) / 3 - 21;
        const float Gab = G[a * 32 + b];
        const float Sb  = G[22 * 32 + b];
        float lo = 0.125f * (wq * wk * Gab + wq * bk * Sa + bq * wk * Sb
                             + bq * bk * (float)NPOS);
        lg[c][k] = lo;
        mx = fmaxf(mx, lo);
    }
    float sum = 0.f;
    #pragma unroll
    for (int k = 0; k < 64; ++k) {
        float e = expf(lg[c][k] - mx);
        lg[c][k] = e; sum += e;
    }
    const float inv = 1.f / sum;
    float Ml[22];
    #pragma unroll
    for (int m = 0; m < 22; ++m) Ml[m] = 0.f;
    float bacc = 0.f;
    #pragma unroll
    for (int k = 0; k < 64; ++k) {
        const float attn = lg[c][k] * inv;
        const int mm = (128 + k) / 3 - 42;
        Ml[mm] = fmaf(attn, cw[128 + k], Ml[mm]);
        bacc   = fmaf(attn, cb[128 + k], bacc);
    }
    #pragma unroll
    for (int m = 0; m < 22; ++m) M[c * 22 + m] = Ml[m];
    betaO[c] = bacc;
}

// Output kernel using precomputed stats: all channel loads independent.
__global__ __launch_bounds__(256) void csa_k4(
    const float* __restrict__ x, const float* __restrict__ lng,
    const float* __restrict__ lnb, const float* __restrict__ stats,
    const float* __restrict__ M, const float* __restrict__ betaO,
    float* __restrict__ out)
{
    const int n = blockIdx.x * 256 + threadIdx.x;
    const f32x2 st = ((const f32x2*)stats)[n];
    const float mu = st[0], rin = st[1];
    float y[22], xr[22];
    #pragma unroll
    for (int m = 0; m < 22; ++m) {
        float v = x[(42 + m) * NPOS + n];
        xr[m] = v;
        y[m] = fmaf((v - mu) * rin, lng[42 + m], lnb[42 + m]);
    }
    #pragma unroll
    for (int c = 0; c < 42; ++c) {
        float v = x[c * NPOS + n];
        float acc = betaO[c];
        #pragma unroll
        for (int m = 0; m < 22; ++m)
            acc = fmaf(M[c * 22 + m], y[m], acc);
        __builtin_nontemporal_store(v + acc, &out[c * NPOS + n]);
    }
    #pragma unroll
    for (int c = 42; c < 64; ++c) {
        float acc = betaO[c];
        #pragma unroll
        for (int m = 0; m < 22; ++m)
            acc = fmaf(M[c * 22 + m], y[m], acc);
        __builtin_nontemporal_store(xr[c - 42] + acc, &out[c * NPOS + n]);
    }
}

// ---------------------------------------------------------------------------
// FALLBACK PATH (round-1, fused stats) — used only if ws is too small.
// ---------------------------------------------------------------------------
__global__ __launch_bounds__(256) void csa_k1f(
    const float* __restrict__ x, const float* __restrict__ lng,
    const float* __restrict__ lnb, float* __restrict__ partials,
    float* __restrict__ gfin, int partial_mode)
{
    __shared__ __align__(16) _Float16 Aar[32][264];
    __shared__ __align__(16) _Float16 Bar[32][264];
    const int tid = threadIdx.x;
    const int lane = tid & 63;
    const int wv = tid >> 6;

    #pragma unroll
    for (int r = 22; r < 32; ++r) {
        const _Float16 v = (r == 22) ? (_Float16)1.0f : (_Float16)0.0f;
        for (int ci = tid; ci < 264; ci += 256) { Aar[r][ci] = v; Bar[r][ci] = v; }
    }
    f32x4 acc00 = {0.f,0.f,0.f,0.f}, acc01 = acc00, acc10 = acc00, acc11 = acc00;
    const int row = lane & 15;
    const int kbase = wv * 64 + ((lane >> 4) << 3);
    const int pos0 = blockIdx.x * (CPB * 256);

    for (int ck = 0; ck < CPB; ++ck) {
        const int n = pos0 + ck * 256 + tid;
        float s = 0.f, sq = 0.f;
        float xv[43];
        #pragma unroll
        for (int c = 0; c < 43; ++c) {
            float v = x[c * NPOS + n];
            xv[c] = v; s += v; sq = fmaf(v, v, sq);
        }
        #pragma unroll
        for (int c = 43; c < 64; ++c) {
            float v = x[c * NPOS + n];
            s += v; sq = fmaf(v, v, sq);
        }
        const float mu  = s * (1.f/64.f);
        const float var = fmaf(-mu, mu, sq * (1.f/64.f));
        const float rin = rsqrtf(fmaxf(var, 0.f) + LN_EPS);
        #pragma unroll
        for (int c = 0; c < 43; ++c) {
            float yv = fmaf((xv[c] - mu) * rin, lng[c], lnb[c]);
            _Float16 h = (_Float16)yv;
            if (c < 22)  Aar[c][tid] = h;
            if (c >= 21) Bar[c - 21][tid] = h;
        }
        __syncthreads();
        #pragma unroll
        for (int s2 = 0; s2 < 2; ++s2) {
            const int kk = kbase + s2 * 32;
            half8 a0 = *(const half8*)&Aar[row][kk];
            half8 a1 = *(const half8*)&Aar[row + 16][kk];
            half8 b0 = *(const half8*)&Bar[row][kk];
            half8 b1 = *(const half8*)&Bar[row + 16][kk];
            acc00 = __builtin_amdgcn_mfma_f32_16x16x32_f16(a0, b0, acc00, 0, 0, 0);
            acc01 = __builtin_amdgcn_mfma_f32_16x16x32_f16(a0, b1, acc01, 0, 0, 0);
            acc10 = __builtin_amdgcn_mfma_f32_16x16x32_f16(a1, b0, acc10, 0, 0, 0);
            acc11 = __builtin_amdgcn_mfma_f32_16x16x32_f16(a1, b1, acc11, 0, 0, 0);
        }
        __syncthreads();
    }
    float* G32 = (float*)&Aar[0][0];
    for (int e = tid; e < 1024; e += 256) G32[e] = 0.f;
    __syncthreads();
    const int r0 = (lane >> 4) * 4, c0 = lane & 15;
    #pragma unroll
    for (int r = 0; r < 4; ++r) {
        atomicAdd(&G32[(r0 + r) * 32 + c0],            acc00[r]);
        atomicAdd(&G32[(r0 + r) * 32 + 16 + c0],       acc01[r]);
        atomicAdd(&G32[(16 + r0 + r) * 32 + c0],       acc10[r]);
        atomicAdd(&G32[(16 + r0 + r) * 32 + 16 + c0],  acc11[r]);
    }
    __syncthreads();
    if (partial_mode) {
        for (int e = tid; e < 1024; e += 256) partials[blockIdx.x * 1024 + e] = G32[e];
    } else {
        for (int e = tid; e < 1024; e += 256) atomicAdd(&gfin[e], G32[e]);
    }
}

__global__ __launch_bounds__(256) void csa_k4f(
    const float* __restrict__ x, const float* __restrict__ lng,
    const float* __restrict__ lnb, const float* __restrict__ M,
    const float* __restrict__ betaO, float* __restrict__ out)
{
    const int n = blockIdx.x * 256 + threadIdx.x;
    float xv[64];
    float s = 0.f, sq = 0.f;
    #pragma unroll
    for (int c = 0; c < 64; ++c) {
        float v = x[c * NPOS + n];
        xv[c] = v; s += v; sq = fmaf(v, v, sq);
    }
    const float mu  = s * (1.f/64.f);
    const float var = fmaf(-mu, mu, sq * (1.f/64.f));
    const float rin = rsqrtf(fmaxf(var, 0.f) + LN_EPS);
    float y[22];
    #pragma unroll
    for (int m = 0; m < 22; ++m)
        y[m] = fmaf((xv[42 + m] - mu) * rin, lng[42 + m], lnb[42 + m]);
    #pragma unroll
    for (int c = 0; c < 64; ++c) {
        float acc = betaO[c];
        #pragma unroll
        for (int m = 0; m < 22; ++m)
            acc = fmaf(M[c * 22 + m], y[m], acc);
        out[c * NPOS + n] = xv[c] + acc;
    }
}

// ---------------------------------------------------------------------------

extern "C" void kernel_launch(void* const* d_in, const int* in_sizes, int n_in,
                              void* d_out, int out_size, void* d_ws, size_t ws_size,
                              hipStream_t stream) {
    const float* x   = (const float*)d_in[0];
    const float* lng = (const float*)d_in[1];
    const float* lnb = (const float*)d_in[2];
    const float* cw  = (const float*)d_in[3];
    const float* cb  = (const float*)d_in[4];
    float* out = (float*)d_out;

    float* wsf = (float*)d_ws;
    float* Gf  = wsf;                     // 1024 floats
    float* Mf  = wsf + 1024;              // 64*22
    float* Bf  = wsf + 1024 + 64 * 22;    // 64

    const size_t statsOffB = 16384;                                   // bytes
    const size_t partOffB  = statsOffB + (size_t)NPOS * 8;            // stats = 4.72 MB
    const size_t needFull  = partOffB + (size_t)K1_BLOCKS * 1024 * 4; // + 3.15 MB

    if (ws_size >= needFull) {
        float* stats = (float*)((char*)d_ws + statsOffB);
        float* Pf    = (float*)((char*)d_ws + partOffB);
        hipLaunchKernelGGL(csa_stats, dim3(NPOS / 1024), dim3(256), 0, stream,
                           x, stats);
        hipLaunchKernelGGL(csa_gram, dim3(K1_BLOCKS), dim3(256), 0, stream,
                           x, lng, lnb, stats, Pf, Gf, 1);
        hipLaunchKernelGGL(csa_k2, dim3(4), dim3(256), 0, stream, Pf, Gf);
        hipLaunchKernelGGL(csa_k3, dim3(1), dim3(64), 0, stream, Gf, cw, cb, Mf, Bf);
        hipLaunchKernelGGL(csa_k4, dim3(NPOS / 256), dim3(256), 0, stream,
                           x, lng, lnb, stats, Mf, Bf, out);
    } else {
        float* Pf = wsf + 4096;
        const size_t need = 16384 + (size_t)K1_BLOCKS * 1024 * 4;
        const int partial = (ws_size >= need) ? 1 : 0;
        if (!partial) hipMemsetAsync(Gf, 0, 1024 * sizeof(float), stream);
        hipLaunchKernelGGL(csa_k1f, dim3(K1_BLOCKS), dim3(256), 0, stream,
                           x, lng, lnb, Pf, Gf, partial);
        if (partial)
            hipLaunchKernelGGL(csa_k2, dim3(4), dim3(256), 0, stream, Pf, Gf);
        hipLaunchKernelGGL(csa_k3, dim3(1), dim3(64), 0, stream, Gf, cw, cb, Mf, Bf);
        hipLaunchKernelGGL(csa_k4f, dim3(NPOS / 256), dim3(256), 0, stream,
                           x, lng, lnb, Mf, Bf, out);
    }
}

// Round 3
// 142.034 us; speedup vs baseline: 1.2129x; 1.2021x over previous
//
#include <hip/hip_runtime.h>

#define NPOS 589824   // 64*96*96
#define LN_EPS 1e-5f

typedef _Float16 half8 __attribute__((ext_vector_type(8)));
typedef float f32x4 __attribute__((ext_vector_type(4)));

#define K1_BLOCKS 768
#define CPB 3   // chunks of 256 positions per block  (768*3*256 == NPOS)

// ws layout (floats): [0,1024) G ; [1024,2432) M 64x22 ; [2432,2496) beta
// [4096, 4096 + K1_BLOCKS*1024) partials  (need = 16KB + 3.15MB, proven available)

// Fused LN-stats + Gram kernel, single-phase loads.
// Each thread: 64 independent channel loads (full MLP), stats accumulated on
// the fly, ch 0..42 parked in LDS as f16, re-read after rin is known.
__global__ __launch_bounds__(256) void csa_k1(
    const float* __restrict__ x, const float* __restrict__ lng,
    const float* __restrict__ lnb, float* __restrict__ partials,
    float* __restrict__ gfin, int partial_mode)
{
    __shared__ _Float16 Xbuf[43][256];               // raw x, ch 0..42 (f16)
    __shared__ __align__(16) _Float16 Aar[32][264];  // y ch 0..21, row22=ones
    __shared__ __align__(16) _Float16 Bar[32][264];  // y ch 21..42, row22=ones
    const int tid = threadIdx.x;
    const int lane = tid & 63;
    const int wv = tid >> 6;

    #pragma unroll
    for (int r = 22; r < 32; ++r) {
        const _Float16 v = (r == 22) ? (_Float16)1.0f : (_Float16)0.0f;
        for (int ci = tid; ci < 264; ci += 256) { Aar[r][ci] = v; Bar[r][ci] = v; }
    }
    f32x4 acc00 = {0.f,0.f,0.f,0.f}, acc01 = acc00, acc10 = acc00, acc11 = acc00;
    const int row = lane & 15;
    const int kbase = wv * 64 + ((lane >> 4) << 3);
    const int pos0 = blockIdx.x * (CPB * 256);

    for (int ck = 0; ck < CPB; ++ck) {
        const int n = pos0 + ck * 256 + tid;
        float s = 0.f, sq = 0.f;
        #pragma unroll
        for (int c = 0; c < 64; ++c) {
            float v = x[c * NPOS + n];          // all 64 loads independent
            s += v; sq = fmaf(v, v, sq);
            if (c < 43) Xbuf[c][tid] = (_Float16)v;   // park, consume later
        }
        const float mu  = s * (1.f/64.f);
        const float var = fmaf(-mu, mu, sq * (1.f/64.f));
        const float rin = rsqrtf(fmaxf(var, 0.f) + LN_EPS);
        #pragma unroll
        for (int c = 0; c < 43; ++c) {
            float v = (float)Xbuf[c][tid];      // same-thread LDS, no barrier
            float yv = fmaf((v - mu) * rin, lng[c], lnb[c]);
            _Float16 h = (_Float16)yv;
            if (c < 22)  Aar[c][tid] = h;
            if (c >= 21) Bar[c - 21][tid] = h;
        }
        __syncthreads();
        #pragma unroll
        for (int s2 = 0; s2 < 2; ++s2) {
            const int kk = kbase + s2 * 32;
            half8 a0 = *(const half8*)&Aar[row][kk];
            half8 a1 = *(const half8*)&Aar[row + 16][kk];
            half8 b0 = *(const half8*)&Bar[row][kk];
            half8 b1 = *(const half8*)&Bar[row + 16][kk];
            acc00 = __builtin_amdgcn_mfma_f32_16x16x32_f16(a0, b0, acc00, 0, 0, 0);
            acc01 = __builtin_amdgcn_mfma_f32_16x16x32_f16(a0, b1, acc01, 0, 0, 0);
            acc10 = __builtin_amdgcn_mfma_f32_16x16x32_f16(a1, b0, acc10, 0, 0, 0);
            acc11 = __builtin_amdgcn_mfma_f32_16x16x32_f16(a1, b1, acc11, 0, 0, 0);
        }
        __syncthreads();
    }
    // block-level reduce of the 4 waves' fragments
    float* G32 = (float*)&Aar[0][0];
    for (int e = tid; e < 1024; e += 256) G32[e] = 0.f;
    __syncthreads();
    const int r0 = (lane >> 4) * 4, c0 = lane & 15;
    #pragma unroll
    for (int r = 0; r < 4; ++r) {
        atomicAdd(&G32[(r0 + r) * 32 + c0],            acc00[r]);
        atomicAdd(&G32[(r0 + r) * 32 + 16 + c0],       acc01[r]);
        atomicAdd(&G32[(16 + r0 + r) * 32 + c0],       acc10[r]);
        atomicAdd(&G32[(16 + r0 + r) * 32 + 16 + c0],  acc11[r]);
    }
    __syncthreads();
    if (partial_mode) {
        for (int e = tid; e < 1024; e += 256) partials[blockIdx.x * 1024 + e] = G32[e];
    } else {
        for (int e = tid; e < 1024; e += 256) atomicAdd(&gfin[e], G32[e]);
    }
}

__global__ __launch_bounds__(256) void csa_k2(const float* __restrict__ partials,
                                              float* __restrict__ gfin)
{
    const int e = blockIdx.x * 256 + threadIdx.x;  // 0..1023
    float s = 0.f;
    for (int b = 0; b < K1_BLOCKS; ++b) s += partials[b * 1024 + e];
    gfin[e] = s;
}

__global__ void csa_k3(const float* __restrict__ G, const float* __restrict__ cw,
                       const float* __restrict__ cb, float* __restrict__ M,
                       float* __restrict__ betaO)
{
    const int c = threadIdx.x;       // 64 threads, one output row each
    __shared__ float lg[64][65];
    const float wq = cw[c], bq = cb[c];
    const int a = c / 3;
    const float Sa = G[a * 32 + 22];
    float mx = -1e30f;
    #pragma unroll
    for (int k = 0; k < 64; ++k) {
        const float wk = cw[64 + k], bk = cb[64 + k];
        const int b = (64 + k) / 3 - 21;
        const float Gab = G[a * 32 + b];
        const float Sb  = G[22 * 32 + b];
        float lo = 0.125f * (wq * wk * Gab + wq * bk * Sa + bq * wk * Sb
                             + bq * bk * (float)NPOS);
        lg[c][k] = lo;
        mx = fmaxf(mx, lo);
    }
    float sum = 0.f;
    #pragma unroll
    for (int k = 0; k < 64; ++k) {
        float e = expf(lg[c][k] - mx);
        lg[c][k] = e; sum += e;
    }
    const float inv = 1.f / sum;
    float Ml[22];
    #pragma unroll
    for (int m = 0; m < 22; ++m) Ml[m] = 0.f;
    float bacc = 0.f;
    #pragma unroll
    for (int k = 0; k < 64; ++k) {
        const float attn = lg[c][k] * inv;
        const int mm = (128 + k) / 3 - 42;
        Ml[mm] = fmaf(attn, cw[128 + k], Ml[mm]);
        bacc   = fmaf(attn, cb[128 + k], bacc);
    }
    #pragma unroll
    for (int m = 0; m < 22; ++m) M[c * 22 + m] = Ml[m];
    betaO[c] = bacc;
}

// Output kernel: recompute stats (single-phase independent loads, xv kept).
__global__ __launch_bounds__(256) void csa_k4(
    const float* __restrict__ x, const float* __restrict__ lng,
    const float* __restrict__ lnb, const float* __restrict__ M,
    const float* __restrict__ betaO, float* __restrict__ out)
{
    const int n = blockIdx.x * 256 + threadIdx.x;
    float xv[64];
    float s = 0.f, sq = 0.f;
    #pragma unroll
    for (int c = 0; c < 64; ++c) {
        float v = x[c * NPOS + n];
        xv[c] = v; s += v; sq = fmaf(v, v, sq);
    }
    const float mu  = s * (1.f/64.f);
    const float var = fmaf(-mu, mu, sq * (1.f/64.f));
    const float rin = rsqrtf(fmaxf(var, 0.f) + LN_EPS);
    float y[22];
    #pragma unroll
    for (int m = 0; m < 22; ++m)
        y[m] = fmaf((xv[42 + m] - mu) * rin, lng[42 + m], lnb[42 + m]);
    #pragma unroll
    for (int c = 0; c < 64; ++c) {
        float acc = betaO[c];
        #pragma unroll
        for (int m = 0; m < 22; ++m)
            acc = fmaf(M[c * 22 + m], y[m], acc);   // M uniform -> SGPR FMAs
        __builtin_nontemporal_store(xv[c] + acc, &out[c * NPOS + n]);
    }
}

extern "C" void kernel_launch(void* const* d_in, const int* in_sizes, int n_in,
                              void* d_out, int out_size, void* d_ws, size_t ws_size,
                              hipStream_t stream) {
    const float* x   = (const float*)d_in[0];
    const float* lng = (const float*)d_in[1];
    const float* lnb = (const float*)d_in[2];
    const float* cw  = (const float*)d_in[3];
    const float* cb  = (const float*)d_in[4];
    float* out = (float*)d_out;

    float* wsf = (float*)d_ws;
    float* Gf  = wsf;                     // 1024 floats
    float* Mf  = wsf + 1024;              // 64*22
    float* Bf  = wsf + 1024 + 64 * 22;    // 64
    float* Pf  = wsf + 4096;              // partials (768 * 1024 floats)

    const size_t need = 16384 + (size_t)K1_BLOCKS * 1024 * 4;  // 3.16 MB
    const int partial = (ws_size >= need) ? 1 : 0;
    if (!partial) hipMemsetAsync(Gf, 0, 1024 * sizeof(float), stream);

    hipLaunchKernelGGL(csa_k1, dim3(K1_BLOCKS), dim3(256), 0, stream,
                       x, lng, lnb, Pf, Gf, partial);
    if (partial)
        hipLaunchKernelGGL(csa_k2, dim3(4), dim3(256), 0, stream, Pf, Gf);
    hipLaunchKernelGGL(csa_k3, dim3(1), dim3(64), 0, stream, Gf, cw, cb, Mf, Bf);
    hipLaunchKernelGGL(csa_k4, dim3(NPOS / 256), dim3(256), 0, stream,
                       x, lng, lnb, Mf, Bf, out);
}